// Round 5
// baseline (352.046 us; speedup 1.0000x reference)
//
#include <hip/hip_runtime.h>
#include <math.h>

#define NROWS 8192
#define NC 10
#define NGRP 8
#define LOG2E_F 1.4426950408889634f

typedef float f32x2 __attribute__((ext_vector_type(2)));

#if __has_builtin(__builtin_amdgcn_exp2f)
#define EXP2F(x) __builtin_amdgcn_exp2f(x)
#else
#define EXP2F(x) exp2f(x)
#endif

// ws layout (floats):
//   P     : [N][12] = {f0..f9, -B2, label_bits}               (12N)
//   L10   : [N][10] = 10*log2(f+1e-45)                        (10N)
//   part  : [nchunk][11][N] = {acc0..9, den} SoA              (11*nchunk*N)
//   part2 : [NGRP][11][N]                                     (11*NGRP*N)
//   bsum  : [32]

__global__ __launch_bounds__(256) void kde_prep(const float* __restrict__ logits,
                                                const int* __restrict__ labels,
                                                float* __restrict__ P,
                                                float* __restrict__ L10) {
    int i = blockIdx.x * 256 + threadIdx.x;
    if (i >= NROWS) return;
    float l[NC];
#pragma unroll
    for (int c = 0; c < NC; ++c) l[c] = logits[i * NC + c];
    float m = l[0];
#pragma unroll
    for (int c = 1; c < NC; ++c) m = fmaxf(m, l[c]);
    float e[NC];
    float sum = 0.f;
#pragma unroll
    for (int c = 0; c < NC; ++c) { e[c] = expf(l[c] - m); sum += e[c]; }
    float lg = 0.f;
#pragma unroll
    for (int c = 0; c < NC; ++c) {
        float f = e[c] / sum;
        P[i * 12 + c] = f;
        L10[i * NC + c] = 10.f * log2f(f + 1e-45f);
        lg += lgammaf(fmaf(10.f, f, 1.f));
    }
    // sum(alphas) == 1/h + C == 20 exactly -> lgamma(sum) constant.
    // Store -B2 (chain seed) and raw label bits.
    float b2 = (lg - lgammaf(20.0f)) * LOG2E_F;
    P[i * 12 + 10] = -b2;
    P[i * 12 + 11] = __int_as_float(labels[i]);
}

// Process one j-row (c0,c1,c2) against 8 i-rows held as 4 f32x2 pairs.
// Exponent chain per slot: e = -B2; e = fmaf(la[c], f[c], e), c = 0..9
// (finB's self-exclusion replicates this scalar-exactly).
#define PROC(c0, c1, c2)                                                       \
    {                                                                          \
        int lab = __builtin_amdgcn_readfirstlane(__float_as_int((c2).w));      \
        float fj[10] = {(c0).x, (c0).y, (c0).z, (c0).w,                        \
                        (c1).x, (c1).y, (c1).z, (c1).w, (c2).x, (c2).y};       \
        f32x2 bi = {(c2).z, (c2).z};                                           \
        f32x2 e[4] = {bi, bi, bi, bi};                                         \
        _Pragma("unroll")                                                      \
        for (int c = 0; c < 10; ++c) {                                         \
            f32x2 q = {fj[c], fj[c]};                                          \
            _Pragma("unroll")                                                  \
            for (int p = 0; p < 4; ++p)                                        \
                e[p] = __builtin_elementwise_fma(laT[p][c], q, e[p]);          \
        }                                                                      \
        f32x2 k0, k1, k2, k3;                                                  \
        k0.x = EXP2F(e[0].x); k0.y = EXP2F(e[0].y);                            \
        k1.x = EXP2F(e[1].x); k1.y = EXP2F(e[1].y);                            \
        k2.x = EXP2F(e[2].x); k2.y = EXP2F(e[2].y);                            \
        k3.x = EXP2F(e[3].x); k3.y = EXP2F(e[3].y);                            \
        den[0] += k0; den[1] += k1; den[2] += k2; den[3] += k3;                \
        switch (lab) {                                                         \
        case 0: acc[0][0]+=k0; acc[1][0]+=k1; acc[2][0]+=k2; acc[3][0]+=k3; break; \
        case 1: acc[0][1]+=k0; acc[1][1]+=k1; acc[2][1]+=k2; acc[3][1]+=k3; break; \
        case 2: acc[0][2]+=k0; acc[1][2]+=k1; acc[2][2]+=k2; acc[3][2]+=k3; break; \
        case 3: acc[0][3]+=k0; acc[1][3]+=k1; acc[2][3]+=k2; acc[3][3]+=k3; break; \
        case 4: acc[0][4]+=k0; acc[1][4]+=k1; acc[2][4]+=k2; acc[3][4]+=k3; break; \
        case 5: acc[0][5]+=k0; acc[1][5]+=k1; acc[2][5]+=k2; acc[3][5]+=k3; break; \
        case 6: acc[0][6]+=k0; acc[1][6]+=k1; acc[2][6]+=k2; acc[3][6]+=k3; break; \
        case 7: acc[0][7]+=k0; acc[1][7]+=k1; acc[2][7]+=k2; acc[3][7]+=k3; break; \
        case 8: acc[0][8]+=k0; acc[1][8]+=k1; acc[2][8]+=k2; acc[3][8]+=k3; break; \
        case 9: acc[0][9]+=k0; acc[1][9]+=k1; acc[2][9]+=k2; acc[3][9]+=k3; break; \
        }                                                                      \
    }

__global__ __launch_bounds__(256, 2) void kde_main(const float* __restrict__ P,
                                                   const float* __restrict__ L10,
                                                   float* __restrict__ part,
                                                   int nchunk) {
    __shared__ float sP[(64 + 2) * 12];        // 64-row tile + 2 prefetch pad rows
    const int tid = threadIdx.x;
    const int i0 = blockIdx.x * 2048 + tid;    // 8 i-rows: i0 + r*256

    f32x2 laT[4][NC];                          // pair p = rows (2p, 2p+1)
#pragma unroll
    for (int p = 0; p < 4; ++p) {
        const float* ra = &L10[(size_t)(i0 + (2 * p) * 256) * NC];
        const float* rb = &L10[(size_t)(i0 + (2 * p + 1) * 256) * NC];
#pragma unroll
        for (int c = 0; c < NC; ++c) laT[p][c] = (f32x2){ra[c], rb[c]};
    }
    f32x2 acc[4][NC];
    f32x2 den[4];
#pragma unroll
    for (int p = 0; p < 4; ++p) {
        den[p] = (f32x2){0.f, 0.f};
#pragma unroll
        for (int c = 0; c < NC; ++c) acc[p][c] = (f32x2){0.f, 0.f};
    }

    const int jsz = NROWS / nchunk;
    const int jbeg = blockIdx.y * jsz;
    for (int js = jbeg; js < jbeg + jsz; js += 64) {
        __syncthreads();
        const float4* gsrc = (const float4*)(P + (size_t)js * 12);
        float4* ldst = (float4*)sP;
        if (tid < 192) ldst[tid] = gsrc[tid];   // 64 rows x 12 floats
        __syncthreads();

        float4 a0 = *(const float4*)&sP[0], a1 = *(const float4*)&sP[4],
               a2 = *(const float4*)&sP[8];
        float4 b0 = *(const float4*)&sP[12], b1 = *(const float4*)&sP[16],
               b2 = *(const float4*)&sP[20];
        for (int jj = 0; jj < 64; jj += 2) {
            const float* nra = &sP[(jj + 2) * 12];   // distance-2 prefetch
            const float* nrb = &sP[(jj + 3) * 12];   // (pad rows when jj=62)
            float4 na0 = *(const float4*)(nra), na1 = *(const float4*)(nra + 4),
                   na2 = *(const float4*)(nra + 8);
            float4 nb0 = *(const float4*)(nrb), nb1 = *(const float4*)(nrb + 4),
                   nb2 = *(const float4*)(nrb + 8);
            PROC(a0, a1, a2)
            PROC(b0, b1, b2)
            a0 = na0; a1 = na1; a2 = na2;
            b0 = nb0; b1 = nb1; b2 = nb2;
        }
    }

    float* pbase = part + (size_t)blockIdx.y * 11 * NROWS;
#pragma unroll
    for (int r = 0; r < 8; ++r) {
        const int p = r >> 1, sl = r & 1;
        float* pb = pbase + (i0 + r * 256);
#pragma unroll
        for (int c = 0; c < NC; ++c) pb[(size_t)c * NROWS] = acc[p][c][sl];
        pb[(size_t)10 * NROWS] = den[p][sl];
    }
}

__global__ __launch_bounds__(256) void kde_finA(const float* __restrict__ part,
                                                float* __restrict__ part2,
                                                int cpg) {
    int i = blockIdx.x * 256 + threadIdx.x;
    int g = blockIdx.y;
    float s[11];
#pragma unroll
    for (int c = 0; c < 11; ++c) s[c] = 0.f;
    for (int k = 0; k < cpg; ++k) {
        const float* pb = part + (size_t)(g * cpg + k) * 11 * NROWS + i;
#pragma unroll
        for (int c = 0; c < 11; ++c) s[c] += pb[(size_t)c * NROWS];
    }
    float* qb = part2 + (size_t)g * 11 * NROWS + i;
#pragma unroll
    for (int c = 0; c < 11; ++c) qb[(size_t)c * NROWS] = s[c];
}

__global__ __launch_bounds__(256) void kde_finB(const float* __restrict__ part2,
                                                const float* __restrict__ P,
                                                const float* __restrict__ L10,
                                                float* __restrict__ bsum) {
    int tid = threadIdx.x;
    int i = blockIdx.x * 256 + tid;
    float acc[11];
#pragma unroll
    for (int c = 0; c < 11; ++c) acc[c] = 0.f;
    for (int g = 0; g < NGRP; ++g) {
        const float* qb = part2 + (size_t)g * 11 * NROWS + i;
#pragma unroll
        for (int c = 0; c < 11; ++c) acc[c] += qb[(size_t)c * NROWS];
    }

    // subtract self-kernel kern[i][i] — bit-identical chain to kde_main
    const float* f = &P[(size_t)i * 12];
    float e = f[10];                            // -B2
#pragma unroll
    for (int c = 0; c < NC; ++c) e = fmaf(L10[(size_t)i * NC + c], f[c], e);
    float self = EXP2F(e);
    int lab = __float_as_int(f[11]);
    float den = acc[10] - self;
    acc[lab] -= self;

    den = fmaxf(den, 1e-10f);                   // clip(den, EPS_DEN, None)
    float per = 0.f;
#pragma unroll
    for (int c = 0; c < NC; ++c) per += fabsf(acc[c] / den - f[c]);

    __shared__ float red[256];
    red[tid] = per;
    __syncthreads();
    for (int off = 128; off > 0; off >>= 1) {
        if (tid < off) red[tid] += red[tid + off];
        __syncthreads();
    }
    if (tid == 0) bsum[blockIdx.x] = red[0];
}

__global__ __launch_bounds__(64) void kde_finC(const float* __restrict__ bsum,
                                               float* __restrict__ out) {
    int t = threadIdx.x;
    float v = (t < 32) ? bsum[t] : 0.f;
#pragma unroll
    for (int off = 32; off > 0; off >>= 1) v += __shfl_down(v, off);
    if (t == 0) out[0] = v * (1.0f / NROWS);
}

extern "C" void kernel_launch(void* const* d_in, const int* in_sizes, int n_in,
                              void* d_out, int out_size, void* d_ws, size_t ws_size,
                              hipStream_t stream) {
    const float* logits = (const float*)d_in[0];
    const int* labels = (const int*)d_in[1];
    float* out = (float*)d_out;
    float* ws = (float*)d_ws;

    int nchunk = 128;
    while (nchunk > NGRP &&
           (size_t)(22 + 11 * (size_t)(nchunk + NGRP)) * NROWS * sizeof(float) + 256 >
               ws_size)
        nchunk >>= 1;
    int cpg = nchunk / NGRP;

    float* P = ws;                                    // 12N
    float* L10 = ws + 12 * NROWS;                     // 10N
    float* part = ws + 22 * NROWS;                    // nchunk*11N
    float* part2 = part + (size_t)nchunk * 11 * NROWS; // NGRP*11N
    float* bsum = part2 + (size_t)NGRP * 11 * NROWS;  // 32

    kde_prep<<<dim3(NROWS / 256), dim3(256), 0, stream>>>(logits, labels, P, L10);
    kde_main<<<dim3(NROWS / 2048, nchunk), dim3(256), 0, stream>>>(P, L10, part, nchunk);
    kde_finA<<<dim3(NROWS / 256, NGRP), dim3(256), 0, stream>>>(part, part2, cpg);
    kde_finB<<<dim3(NROWS / 256), dim3(256), 0, stream>>>(part2, P, L10, bsum);
    kde_finC<<<dim3(1), dim3(64), 0, stream>>>(bsum, out);
}

// Round 6
// 91.701 us; speedup vs baseline: 3.8391x; 3.8391x over previous
//
#include <hip/hip_runtime.h>
#include <math.h>

#define NROWS 8192
#define NC 10
#define NGRP 8
#define LOG2E_F 1.4426950408889634f

typedef float f32x2 __attribute__((ext_vector_type(2)));

#if __has_builtin(__builtin_amdgcn_exp2f)
#define EXP2F(x) __builtin_amdgcn_exp2f(x)
#else
#define EXP2F(x) exp2f(x)
#endif

// ws layout (floats):
//   P     : [N][12] = {f0..f9, -B2, label_bits}               (12N)
//   L10   : [N][10] = 10*log2(f+1e-45)                        (10N)
//   part  : [nchunk][11][N] = {acc0..9, den} SoA              (11*nchunk*N)
//   part2 : [NGRP][11][N]                                     (11*NGRP*N)
//   bsum  : [32]

__global__ __launch_bounds__(256) void kde_prep(const float* __restrict__ logits,
                                                const int* __restrict__ labels,
                                                float* __restrict__ P,
                                                float* __restrict__ L10) {
    int i = blockIdx.x * 256 + threadIdx.x;
    if (i >= NROWS) return;
    float l[NC];
#pragma unroll
    for (int c = 0; c < NC; ++c) l[c] = logits[i * NC + c];
    float m = l[0];
#pragma unroll
    for (int c = 1; c < NC; ++c) m = fmaxf(m, l[c]);
    float e[NC];
    float sum = 0.f;
#pragma unroll
    for (int c = 0; c < NC; ++c) { e[c] = expf(l[c] - m); sum += e[c]; }
    float lg = 0.f;
#pragma unroll
    for (int c = 0; c < NC; ++c) {
        float f = e[c] / sum;
        P[i * 12 + c] = f;
        L10[i * NC + c] = 10.f * log2f(f + 1e-45f);
        lg += lgammaf(fmaf(10.f, f, 1.f));
    }
    // sum(alphas) == 1/h + C == 20 exactly -> lgamma(sum) is a constant.
    float b2 = (lg - lgammaf(20.0f)) * LOG2E_F;
    P[i * 12 + 10] = -b2;
    P[i * 12 + 11] = __int_as_float(labels[i]);
}

// exponent = dot(la, f_j) - B2_j, packed tree. init lane.x carries -B2.
// finB's self-exclusion calls this SAME function -> bit-identical.
__device__ __forceinline__ float kern_exponent(const f32x2 la[5],
                                               float4 c0, float4 c1, float4 c2) {
    f32x2 q0 = {c0.x, c0.y}, q1 = {c0.z, c0.w};
    f32x2 q2 = {c1.x, c1.y}, q3 = {c1.z, c1.w};
    f32x2 q4 = {c2.x, c2.y};
    f32x2 init = {c2.z, 0.f};
    f32x2 cA = __builtin_elementwise_fma(la[0], q0,
               __builtin_elementwise_fma(la[2], q2, la[4] * q4));
    f32x2 cB = __builtin_elementwise_fma(la[1], q1,
               __builtin_elementwise_fma(la[3], q3, init));
    f32x2 cS = cA + cB;
    return cS.x + cS.y;
}

#define PROC(c0, c1, c2)                                                       \
    {                                                                          \
        int lab = __builtin_amdgcn_readfirstlane(__float_as_int((c2).w));      \
        float k0 = EXP2F(kern_exponent(la[0], c0, c1, c2));                    \
        float k1 = EXP2F(kern_exponent(la[1], c0, c1, c2));                    \
        float k2 = EXP2F(kern_exponent(la[2], c0, c1, c2));                    \
        float k3 = EXP2F(kern_exponent(la[3], c0, c1, c2));                    \
        den[0] += k0; den[1] += k1; den[2] += k2; den[3] += k3;                \
        switch (lab) {                                                         \
        case 0: acc[0][0]+=k0; acc[1][0]+=k1; acc[2][0]+=k2; acc[3][0]+=k3; break; \
        case 1: acc[0][1]+=k0; acc[1][1]+=k1; acc[2][1]+=k2; acc[3][1]+=k3; break; \
        case 2: acc[0][2]+=k0; acc[1][2]+=k1; acc[2][2]+=k2; acc[3][2]+=k3; break; \
        case 3: acc[0][3]+=k0; acc[1][3]+=k1; acc[2][3]+=k2; acc[3][3]+=k3; break; \
        case 4: acc[0][4]+=k0; acc[1][4]+=k1; acc[2][4]+=k2; acc[3][4]+=k3; break; \
        case 5: acc[0][5]+=k0; acc[1][5]+=k1; acc[2][5]+=k2; acc[3][5]+=k3; break; \
        case 6: acc[0][6]+=k0; acc[1][6]+=k1; acc[2][6]+=k2; acc[3][6]+=k3; break; \
        case 7: acc[0][7]+=k0; acc[1][7]+=k1; acc[2][7]+=k2; acc[3][7]+=k3; break; \
        case 8: acc[0][8]+=k0; acc[1][8]+=k1; acc[2][8]+=k2; acc[3][8]+=k3; break; \
        case 9: acc[0][9]+=k0; acc[1][9]+=k1; acc[2][9]+=k2; acc[3][9]+=k3; break; \
        }                                                                      \
    }

__global__ __launch_bounds__(256) void kde_main(const float* __restrict__ P,
                                                const float* __restrict__ L10,
                                                float* __restrict__ part,
                                                int nchunk) {
    __shared__ float sP[(64 + 2) * 12];       // 64-row tile + 2 prefetch pad rows
    const int tid = threadIdx.x;
    const int i0 = blockIdx.x * 1024 + tid;   // 4 i-rows: i0 + r*256

    f32x2 la[4][5];
#pragma unroll
    for (int r = 0; r < 4; ++r)
#pragma unroll
        for (int c = 0; c < 5; ++c)
            la[r][c] = *(const f32x2*)&L10[(size_t)(i0 + r * 256) * NC + 2 * c];

    float acc[4][NC];
    float den[4] = {0.f, 0.f, 0.f, 0.f};
#pragma unroll
    for (int r = 0; r < 4; ++r)
#pragma unroll
        for (int c = 0; c < NC; ++c) acc[r][c] = 0.f;

    const int jsz = NROWS / nchunk;
    const int jbeg = blockIdx.y * jsz;
    for (int js = jbeg; js < jbeg + jsz; js += 64) {
        __syncthreads();
        const float4* gsrc = (const float4*)(P + (size_t)js * 12);
        float4* ldst = (float4*)sP;
        if (tid < 192) ldst[tid] = gsrc[tid];   // 64 rows x 12 floats
        __syncthreads();

        float4 a0 = *(const float4*)&sP[0], a1 = *(const float4*)&sP[4],
               a2 = *(const float4*)&sP[8];
        float4 b0 = *(const float4*)&sP[12], b1 = *(const float4*)&sP[16],
               b2 = *(const float4*)&sP[20];
        for (int jj = 0; jj < 64; jj += 2) {
            const float* nra = &sP[(jj + 2) * 12];   // distance-2 prefetch
            const float* nrb = &sP[(jj + 3) * 12];   // (pad rows when jj=62)
            float4 na0 = *(const float4*)(nra), na1 = *(const float4*)(nra + 4),
                   na2 = *(const float4*)(nra + 8);
            float4 nb0 = *(const float4*)(nrb), nb1 = *(const float4*)(nrb + 4),
                   nb2 = *(const float4*)(nrb + 8);
            PROC(a0, a1, a2)
            PROC(b0, b1, b2)
            a0 = na0; a1 = na1; a2 = na2;
            b0 = nb0; b1 = nb1; b2 = nb2;
        }
    }

    // SoA: part[(chunk*11 + c)*N + i] — coalesced
    float* pbase = part + (size_t)blockIdx.y * 11 * NROWS;
#pragma unroll
    for (int r = 0; r < 4; ++r) {
        float* pb = pbase + (i0 + r * 256);
#pragma unroll
        for (int c = 0; c < NC; ++c) pb[(size_t)c * NROWS] = acc[r][c];
        pb[(size_t)10 * NROWS] = den[r];
    }
}

__global__ __launch_bounds__(256) void kde_finA(const float* __restrict__ part,
                                                float* __restrict__ part2,
                                                int cpg) {
    int i = blockIdx.x * 256 + threadIdx.x;
    int g = blockIdx.y;
    float s[11];
#pragma unroll
    for (int c = 0; c < 11; ++c) s[c] = 0.f;
    for (int k = 0; k < cpg; ++k) {
        const float* pb = part + (size_t)(g * cpg + k) * 11 * NROWS + i;
#pragma unroll
        for (int c = 0; c < 11; ++c) s[c] += pb[(size_t)c * NROWS];
    }
    float* qb = part2 + (size_t)g * 11 * NROWS + i;
#pragma unroll
    for (int c = 0; c < 11; ++c) qb[(size_t)c * NROWS] = s[c];
}

__global__ __launch_bounds__(256) void kde_finB(const float* __restrict__ part2,
                                                const float* __restrict__ P,
                                                const float* __restrict__ L10,
                                                float* __restrict__ bsum) {
    int tid = threadIdx.x;
    int i = blockIdx.x * 256 + tid;
    float acc[11];
#pragma unroll
    for (int c = 0; c < 11; ++c) acc[c] = 0.f;
    for (int g = 0; g < NGRP; ++g) {
        const float* qb = part2 + (size_t)g * 11 * NROWS + i;
#pragma unroll
        for (int c = 0; c < 11; ++c) acc[c] += qb[(size_t)c * NROWS];
    }

    // subtract self-kernel kern[i][i] — bit-identical packed chain
    f32x2 la[5];
#pragma unroll
    for (int c = 0; c < 5; ++c)
        la[c] = *(const f32x2*)&L10[(size_t)i * NC + 2 * c];
    float4 v0 = *(const float4*)&P[(size_t)i * 12];
    float4 v1 = *(const float4*)&P[(size_t)i * 12 + 4];
    float4 v2 = *(const float4*)&P[(size_t)i * 12 + 8];
    float self = EXP2F(kern_exponent(la, v0, v1, v2));
    int lab = __float_as_int(v2.w);
    float den = acc[10] - self;
    acc[lab] -= self;

    den = fmaxf(den, 1e-10f);                   // clip(den, EPS_DEN, None)
    float per = 0.f;
    const float* f = &P[(size_t)i * 12];
#pragma unroll
    for (int c = 0; c < NC; ++c) per += fabsf(acc[c] / den - f[c]);

    __shared__ float red[256];
    red[tid] = per;
    __syncthreads();
    for (int off = 128; off > 0; off >>= 1) {
        if (tid < off) red[tid] += red[tid + off];
        __syncthreads();
    }
    if (tid == 0) bsum[blockIdx.x] = red[0];
}

__global__ __launch_bounds__(64) void kde_finC(const float* __restrict__ bsum,
                                               float* __restrict__ out) {
    int t = threadIdx.x;
    float v = (t < 32) ? bsum[t] : 0.f;
#pragma unroll
    for (int off = 32; off > 0; off >>= 1) v += __shfl_down(v, off);
    if (t == 0) out[0] = v * (1.0f / NROWS);
}

extern "C" void kernel_launch(void* const* d_in, const int* in_sizes, int n_in,
                              void* d_out, int out_size, void* d_ws, size_t ws_size,
                              hipStream_t stream) {
    const float* logits = (const float*)d_in[0];
    const int* labels = (const int*)d_in[1];
    float* out = (float*)d_out;
    float* ws = (float*)d_ws;

    int nchunk = 128;
    while (nchunk > NGRP &&
           (size_t)(22 + 11 * (size_t)(nchunk + NGRP)) * NROWS * sizeof(float) + 256 >
               ws_size)
        nchunk >>= 1;
    int cpg = nchunk / NGRP;

    float* P = ws;                                     // 12N
    float* L10 = ws + 12 * NROWS;                      // 10N
    float* part = ws + 22 * NROWS;                     // nchunk*11N
    float* part2 = part + (size_t)nchunk * 11 * NROWS; // NGRP*11N
    float* bsum = part2 + (size_t)NGRP * 11 * NROWS;   // 32

    kde_prep<<<dim3(NROWS / 256), dim3(256), 0, stream>>>(logits, labels, P, L10);
    kde_main<<<dim3(NROWS / 1024, nchunk), dim3(256), 0, stream>>>(P, L10, part, nchunk);
    kde_finA<<<dim3(NROWS / 256, NGRP), dim3(256), 0, stream>>>(part, part2, cpg);
    kde_finB<<<dim3(NROWS / 256), dim3(256), 0, stream>>>(part2, P, L10, bsum);
    kde_finC<<<dim3(1), dim3(64), 0, stream>>>(bsum, out);
}

// Round 7
// 39.341 us; speedup vs baseline: 8.9487x; 2.3310x over previous
//
#include <hip/hip_runtime.h>
#include <math.h>

#define NROWS 8192
#define NC 10
#define NCHUNK 32
#define LOG2E_F 1.4426950408889634f

typedef short bf16x8 __attribute__((ext_vector_type(8)));   // MFMA a/b frag (guide-verified type)
typedef float f32x4 __attribute__((ext_vector_type(4)));    // MFMA c/d frag
typedef unsigned short u16;
typedef unsigned int u32;

#if __has_builtin(__builtin_amdgcn_exp2f)
#define EXP2F(x) __builtin_amdgcn_exp2f(x)
#else
#define EXP2F(x) exp2f(x)
#endif

__device__ __forceinline__ u16 f2bf(float x) {              // RNE f32->bf16 (deterministic)
    u32 u = __float_as_uint(x);
    return (u16)((u + 0x7FFFu + ((u >> 16) & 1u)) >> 16);
}
__device__ __forceinline__ float bf2f(u16 b) { return __uint_as_float(((u32)b) << 16); }
__device__ __forceinline__ u32 cvtpk_bf16(float lo, float hi) {
    u32 r; asm("v_cvt_pk_bf16_f32 %0, %1, %2" : "=v"(r) : "v"(lo), "v"(hi)); return r;
}

// ws layout:
//   P    : [N][12] f32 = {f0..f9, -B2, label_bits}
//   L10  : [N][10] f32 = 10*log2(f+1e-45)
//   AFP  : [512 jt16][64 lane][8] bf16  QK A-frags (j side: Fhi/Flo/-B2 hi/lo)
//   BLP  : [512 it16][64 lane][8] bf16  QK B-frags (i side: L10hi/lo, ones)
//   OHP  : [256 jt32][64 lane][8] bf16  PV B-frags (onehot + den-ones col 10)
//   part : [NCHUNK][11][N] f32
//   bsum : [32]

__global__ __launch_bounds__(256) void kde_prep(const float* __restrict__ logits,
                                                const int* __restrict__ labels,
                                                float* __restrict__ P,
                                                float* __restrict__ L10) {
    int i = blockIdx.x * 256 + threadIdx.x;
    if (i >= NROWS) return;
    float l[NC];
#pragma unroll
    for (int c = 0; c < NC; ++c) l[c] = logits[i * NC + c];
    float m = l[0];
#pragma unroll
    for (int c = 1; c < NC; ++c) m = fmaxf(m, l[c]);
    float e[NC];
    float sum = 0.f;
#pragma unroll
    for (int c = 0; c < NC; ++c) { e[c] = expf(l[c] - m); sum += e[c]; }
    float lg = 0.f;
#pragma unroll
    for (int c = 0; c < NC; ++c) {
        float f = e[c] / sum;
        P[i * 12 + c] = f;
        L10[i * NC + c] = 10.f * log2f(f + 1e-45f);
        lg += lgammaf(fmaf(10.f, f, 1.f));
    }
    // sum(alphas) == 1/h + C == 20 exactly -> lgamma(sum) is a constant
    float b2 = (lg - lgammaf(20.0f)) * LOG2E_F;
    P[i * 12 + 10] = -b2;
    P[i * 12 + 11] = __int_as_float(labels[i]);
}

// Pack MFMA operand fragments. Logical k(h,e) = h*8+e used IDENTICALLY for both
// sides of each MFMA -> any hardware k-permutation cancels.
__global__ __launch_bounds__(256) void kde_pack(const float* __restrict__ P,
                                                const float* __restrict__ L10,
                                                const int* __restrict__ labels,
                                                u16* __restrict__ AFP,
                                                u16* __restrict__ BLP,
                                                u16* __restrict__ OHP) {
    union U8 { u16 s[8]; int4 v; };
    const int bx = blockIdx.x, tid = threadIdx.x;
    if (bx < 128) {                       // ---- AFP: j side
        int t = bx * 256 + tid;           // (jt16, lane)
        int l = t & 63, jt = t >> 6;
        int j = jt * 16 + (l & 15), h = l >> 4;
        const float* f = &P[(size_t)j * 12];
        u16 FH[10], FL[10];
#pragma unroll
        for (int c = 0; c < 10; ++c) {
            FH[c] = f2bf(f[c]);
            FL[c] = f2bf(f[c] - bf2f(FH[c]));
        }
        float nb2 = f[10];
        u16 bh = f2bf(nb2);
        u16 bl = f2bf(nb2 - bf2f(bh));
        U8 o;
        if (h == 0) {      // k=0..7   : Fhi[0..7]
            o.s[0]=FH[0]; o.s[1]=FH[1]; o.s[2]=FH[2]; o.s[3]=FH[3];
            o.s[4]=FH[4]; o.s[5]=FH[5]; o.s[6]=FH[6]; o.s[7]=FH[7];
        } else if (h == 1) { // k=8..15 : Fhi[8,9], Flo[0..5]
            o.s[0]=FH[8]; o.s[1]=FH[9]; o.s[2]=FL[0]; o.s[3]=FL[1];
            o.s[4]=FL[2]; o.s[5]=FL[3]; o.s[6]=FL[4]; o.s[7]=FL[5];
        } else if (h == 2) { // k=16..23: Flo[6..9], Fhi[0..3]
            o.s[0]=FL[6]; o.s[1]=FL[7]; o.s[2]=FL[8]; o.s[3]=FL[9];
            o.s[4]=FH[0]; o.s[5]=FH[1]; o.s[6]=FH[2]; o.s[7]=FH[3];
        } else {             // k=24..31: Fhi[4..9], -B2hi, -B2lo
            o.s[0]=FH[4]; o.s[1]=FH[5]; o.s[2]=FH[6]; o.s[3]=FH[7];
            o.s[4]=FH[8]; o.s[5]=FH[9]; o.s[6]=bh;    o.s[7]=bl;
        }
        *(int4*)&AFP[(size_t)t * 8] = o.v;
    } else if (bx < 256) {                // ---- BLP: i side
        int t = (bx - 128) * 256 + tid;
        int l = t & 63, it = t >> 6;
        int i = it * 16 + (l & 15), h = l >> 4;
        u16 LH[10], LL[10];
#pragma unroll
        for (int c = 0; c < 10; ++c) {
            float L = L10[(size_t)i * NC + c];
            LH[c] = f2bf(L);
            LL[c] = f2bf(L - bf2f(LH[c]));
        }
        const u16 ONE = 0x3F80;
        U8 o;
        if (h == 0) {       // k=0..7   : L10hi[0..7]
            o.s[0]=LH[0]; o.s[1]=LH[1]; o.s[2]=LH[2]; o.s[3]=LH[3];
            o.s[4]=LH[4]; o.s[5]=LH[5]; o.s[6]=LH[6]; o.s[7]=LH[7];
        } else if (h == 1) { // k=8..15 : L10hi[8,9], L10hi[0..5]
            o.s[0]=LH[8]; o.s[1]=LH[9]; o.s[2]=LH[0]; o.s[3]=LH[1];
            o.s[4]=LH[2]; o.s[5]=LH[3]; o.s[6]=LH[4]; o.s[7]=LH[5];
        } else if (h == 2) { // k=16..23: L10hi[6..9], L10lo[0..3]
            o.s[0]=LH[6]; o.s[1]=LH[7]; o.s[2]=LH[8]; o.s[3]=LH[9];
            o.s[4]=LL[0]; o.s[5]=LL[1]; o.s[6]=LL[2]; o.s[7]=LL[3];
        } else {             // k=24..31: L10lo[4..9], 1, 1
            o.s[0]=LL[4]; o.s[1]=LL[5]; o.s[2]=LL[6]; o.s[3]=LL[7];
            o.s[4]=LL[8]; o.s[5]=LL[9]; o.s[6]=ONE;   o.s[7]=ONE;
        }
        *(int4*)&BLP[(size_t)t * 8] = o.v;
    } else {                              // ---- OHP: onehot + den-ones
        int t = (bx - 256) * 256 + tid;   // (jt32, lane), 16384 threads
        int l = t & 63, jt = t >> 6;
        int c = l & 15, h = l >> 4;
        U8 o;
#pragma unroll
        for (int e = 0; e < 8; ++e) {
            int j = jt * 32 + ((e >> 2) << 4) + h * 4 + (e & 3);  // j_log(h,e)
            int lab = labels[j];
            o.s[e] = (c == lab || c == 10) ? (u16)0x3F80 : (u16)0;
        }
        *(int4*)&OHP[(size_t)t * 8] = o.v;
    }
}

__global__ __launch_bounds__(256) void kde_main(const u16* __restrict__ AFP_,
                                                const u16* __restrict__ BLP_,
                                                const u16* __restrict__ OHP_,
                                                float* __restrict__ part) {
    const bf16x8* AFP = (const bf16x8*)AFP_;
    const bf16x8* BLP = (const bf16x8*)BLP_;
    const bf16x8* OHP = (const bf16x8*)OHP_;
    const int tid = threadIdx.x, w = tid >> 6, l = tid & 63;
    const int ib = blockIdx.x, chunk = blockIdx.y;

    bf16x8 bl[4];                 // wave's 4 i-tile B-frags
#pragma unroll
    for (int t = 0; t < 4; ++t) bl[t] = BLP[(size_t)(ib * 16 + w * 4 + t) * 64 + l];

    const f32x4 z = {0.f, 0.f, 0.f, 0.f};
    f32x4 acc[4];
#pragma unroll
    for (int t = 0; t < 4; ++t) acc[t] = z;

    for (int jt = chunk * 8; jt < chunk * 8 + 8; ++jt) {   // jt32 tiles
        bf16x8 af0 = AFP[(size_t)(2 * jt) * 64 + l];
        bf16x8 af1 = AFP[(size_t)(2 * jt + 1) * 64 + l];
        bf16x8 oh  = OHP[(size_t)jt * 64 + l];
#pragma unroll
        for (int t = 0; t < 4; ++t) {
            f32x4 s0 = __builtin_amdgcn_mfma_f32_16x16x32_bf16(af0, bl[t], z, 0, 0, 0);
            f32x4 s1 = __builtin_amdgcn_mfma_f32_16x16x32_bf16(af1, bl[t], z, 0, 0, 0);
            union { bf16x8 v; u32 u[4]; } kf;
            kf.u[0] = cvtpk_bf16(EXP2F(s0.x), EXP2F(s0.y));
            kf.u[1] = cvtpk_bf16(EXP2F(s0.z), EXP2F(s0.w));
            kf.u[2] = cvtpk_bf16(EXP2F(s1.x), EXP2F(s1.y));
            kf.u[3] = cvtpk_bf16(EXP2F(s1.z), EXP2F(s1.w));
            acc[t] = __builtin_amdgcn_mfma_f32_16x16x32_bf16(kf.v, oh, acc[t], 0, 0, 0);
        }
    }

    const int c = l & 15, h = l >> 4;
    if (c < 11) {
#pragma unroll
        for (int t = 0; t < 4; ++t) {
            float* dst = part + ((size_t)(chunk * 11 + c)) * NROWS +
                         ib * 256 + (w * 4 + t) * 16 + h * 4;
            *(f32x4*)dst = acc[t];
        }
    }
}

__global__ __launch_bounds__(256) void kde_finB(const float* __restrict__ part,
                                                const float* __restrict__ P,
                                                const float* __restrict__ L10,
                                                float* __restrict__ bsum) {
    const int tid = threadIdx.x;
    const int i = blockIdx.x * 256 + tid;
    float acc[11];
#pragma unroll
    for (int c = 0; c < 11; ++c) acc[c] = 0.f;
    for (int ch = 0; ch < NCHUNK; ++ch) {
#pragma unroll
        for (int c = 0; c < 11; ++c)
            acc[c] += part[((size_t)(ch * 11 + c)) * NROWS + i];
    }

    // self-kernel: reconstruct the SAME bf16 operand values as kde_pack,
    // sum products (exact in f32) in a fixed order, exp2 + bf16-round like main.
    const float* f = &P[(size_t)i * 12];
    float FH[10], FL[10], LH[10], LL[10];
#pragma unroll
    for (int c = 0; c < 10; ++c) {
        u16 a = f2bf(f[c]);            FH[c] = bf2f(a);
        u16 b = f2bf(f[c] - FH[c]);    FL[c] = bf2f(b);
        float L = L10[(size_t)i * NC + c];
        u16 x = f2bf(L);               LH[c] = bf2f(x);
        u16 y = f2bf(L - LH[c]);       LL[c] = bf2f(y);
    }
    float nb2 = f[10];
    float BH = bf2f(f2bf(nb2));
    float BL = bf2f(f2bf(nb2 - BH));
    float S = 0.f;
#pragma unroll
    for (int c = 0; c < 10; ++c) S += FH[c] * LH[c];
#pragma unroll
    for (int c = 0; c < 10; ++c) S += FL[c] * LH[c];
#pragma unroll
    for (int c = 0; c < 10; ++c) S += FH[c] * LL[c];
    S += BH; S += BL;
    float self = bf2f((u16)(cvtpk_bf16(EXP2F(S), 0.f) & 0xFFFFu));  // bf16-rounded like PV input
    int lab = __float_as_int(f[11]);
    float den = acc[10] - self;
    switch (lab) {
#define CASE(c) case c: acc[c] -= self; break;
        CASE(0) CASE(1) CASE(2) CASE(3) CASE(4)
        CASE(5) CASE(6) CASE(7) CASE(8) CASE(9)
#undef CASE
    }

    den = fmaxf(den, 1e-10f);   // clip(den, EPS_DEN, None)
    float per = 0.f;
#pragma unroll
    for (int c = 0; c < NC; ++c) per += fabsf(acc[c] / den - f[c]);

    __shared__ float red[256];
    red[tid] = per;
    __syncthreads();
    for (int off = 128; off > 0; off >>= 1) {
        if (tid < off) red[tid] += red[tid + off];
        __syncthreads();
    }
    if (tid == 0) bsum[blockIdx.x] = red[0];
}

__global__ __launch_bounds__(64) void kde_finC(const float* __restrict__ bsum,
                                               float* __restrict__ out) {
    int t = threadIdx.x;
    float v = (t < 32) ? bsum[t] : 0.f;
#pragma unroll
    for (int off = 32; off > 0; off >>= 1) v += __shfl_down(v, off);
    if (t == 0) out[0] = v * (1.0f / NROWS);
}

extern "C" void kernel_launch(void* const* d_in, const int* in_sizes, int n_in,
                              void* d_out, int out_size, void* d_ws, size_t ws_size,
                              hipStream_t stream) {
    const float* logits = (const float*)d_in[0];
    const int* labels = (const int*)d_in[1];
    float* out = (float*)d_out;
    float* ws = (float*)d_ws;

    float* P   = ws;                                   // 12N f32
    float* L10 = ws + 12 * NROWS;                      // 10N f32
    u16* AFP = (u16*)(ws + 22 * NROWS);                // 512K  (16N f32-equiv)
    u16* BLP = AFP + (size_t)NROWS * 32;               // 512K  (16N)
    u16* OHP = BLP + (size_t)NROWS * 32;               // 256K  (8N)
    float* part = ws + 62 * NROWS;                     // NCHUNK*11*N f32
    float* bsum = part + (size_t)NCHUNK * 11 * NROWS;  // 32

    kde_prep<<<dim3(NROWS / 256), dim3(256), 0, stream>>>(logits, labels, P, L10);
    kde_pack<<<dim3(320), dim3(256), 0, stream>>>(P, L10, labels, AFP, BLP, OHP);
    kde_main<<<dim3(NROWS / 256, NCHUNK), dim3(256), 0, stream>>>(AFP, BLP, OHP, part);
    kde_finB<<<dim3(NROWS / 256), dim3(256), 0, stream>>>(part, P, L10, bsum);
    kde_finC<<<dim3(1), dim3(64), 0, stream>>>(bsum, out);
}